// Round 5
// baseline (812.024 us; speedup 1.0000x reference)
//
#include <hip/hip_runtime.h>
#include <hip/hip_bf16.h>
#include <stdint.h>

// Shapes: B=32, L=256, D=1024, ALIGN=1024, FF=2048, NC=3
// Precision plan:
//  - F proj, E scores: bf16x3 split (~fp32) -- the softmax-sensitive path
//  - attn, betas/alphas, V=tanh(Cat@W_G): fp16 single (store rounding dominates)
//  - classifier: fp32 VALU skinny GEMMs (exact, M=32 is tiny)

typedef __attribute__((ext_vector_type(8))) short    short8_t;   // 8 bf16
typedef __attribute__((ext_vector_type(4))) float    float4_t;
typedef __attribute__((ext_vector_type(8))) _Float16 half8_t;
typedef __attribute__((ext_vector_type(4))) _Float16 half4_t;

#define DEVI static __device__ __forceinline__

DEVI short f2bf(float f) {
  union { float f; unsigned u; } v; v.f = f;
  unsigned r = v.u + 0x7fffu + ((v.u >> 16) & 1u);   // RNE
  return (short)(r >> 16);
}
DEVI float bf2f(short s) {
  union { unsigned u; float f; } v;
  v.u = ((unsigned)(unsigned short)s) << 16;
  return v.f;
}
DEVI void split2(float x, short& hi, short& lo) {
  hi = f2bf(x);
  lo = f2bf(x - bf2f(hi));
}
DEVI float fast_tanh(float x) {
  float e = __expf(2.0f * x);
  return 1.0f - 2.0f / (e + 1.0f);
}
DEVI void gload16(const void* g, void* l) {
  // async global->LDS, 16B/lane; LDS dest = wave-uniform base + lane*16
  __builtin_amdgcn_global_load_lds(
      (const __attribute__((address_space(1))) void*)g,
      (__attribute__((address_space(3))) void*)l, 16, 0, 0);
}

// ---------------------------------------------------------------------------
// Split-bf16 NT GEMM (A=Ah+Al, B=Bh+Bl), 128x128 tile, BK=32, 4 waves,
// 3 MFMAs per product (hh,hl,lh). Async global_load_lds staging with XOR
// chunk swizzle (slot = chunk ^ ((row>>1)&3)) -> 0 LDS bank conflicts.
// blockIdx.z = batch*kslices + kslice.
// OUT_MODE: 0 = fp32 atomicAdd (split-K; C pre-zeroed), 1 = split bf16 store.
// ---------------------------------------------------------------------------
template <int DO_TANH, int OUT_MODE>
__global__ __launch_bounds__(256) void gemm_nt_split(
    const short* __restrict__ Ah, const short* __restrict__ Al, int lda, long sA,
    const short* __restrict__ Bh, const short* __restrict__ Bl, int ldb, long sB,
    void* __restrict__ Ch, void* __restrict__ Cl, int ldc, long sC,
    int M, int K, int kslices)
{
  __shared__ __align__(16) short Ash[128 * 32];
  __shared__ __align__(16) short Asl[128 * 32];
  __shared__ __align__(16) short Bsh[128 * 32];
  __shared__ __align__(16) short Bsl[128 * 32];

  const int z  = blockIdx.z;
  const int zb = z / kslices;
  const int zk = z - zb * kslices;
  const int Ksub = K / kslices;
  const int kbeg = zk * Ksub;

  Ah += (size_t)zb * sA;  Al += (size_t)zb * sA;
  Bh += (size_t)zb * sB;  Bl += (size_t)zb * sB;

  const int row0 = blockIdx.x * 128;
  const int col0 = blockIdx.y * 128;
  const int t = threadIdx.x, lane = t & 63, wave = t >> 6;
  const int wr = wave >> 1, wc = wave & 1;
  const int m15 = lane & 15, q = lane >> 4;

  // staging: wave w stages rows [w*32, w*32+32) of each tile, 16 rows/call.
  // lane l -> row base+(l>>2), LDS slot l&3; global chunk (l&3)^((l>>3)&3).
  const int srow = wave * 32 + (lane >> 2);
  const int cg   = ((lane & 3) ^ ((lane >> 3) & 3)) * 8;
  const short* gAh0 = Ah + (size_t)(row0 + srow) * lda + kbeg + cg;
  const short* gAh1 = gAh0 + (size_t)16 * lda;
  const short* gAl0 = Al + (size_t)(row0 + srow) * lda + kbeg + cg;
  const short* gAl1 = gAl0 + (size_t)16 * lda;
  const short* gBh0 = Bh + (size_t)(col0 + srow) * ldb + kbeg + cg;
  const short* gBh1 = gBh0 + (size_t)16 * ldb;
  const short* gBl0 = Bl + (size_t)(col0 + srow) * ldb + kbeg + cg;
  const short* gBl1 = gBl0 + (size_t)16 * ldb;
  short* lAh0 = &Ash[(wave * 32) * 32]; short* lAh1 = lAh0 + 16 * 32;
  short* lAl0 = &Asl[(wave * 32) * 32]; short* lAl1 = lAl0 + 16 * 32;
  short* lBh0 = &Bsh[(wave * 32) * 32]; short* lBh1 = lBh0 + 16 * 32;
  short* lBl0 = &Bsl[(wave * 32) * 32]; short* lBl1 = lBl0 + 16 * 32;

  // fragment LDS offsets: row R+m15 wants chunk q at slot q ^ ((m15>>1)&3)
  const int fs = (q ^ ((m15 >> 1) & 3)) * 8;
  int aoff[4], boff[4];
#pragma unroll
  for (int i = 0; i < 4; ++i) {
    aoff[i] = (wr * 64 + i * 16 + m15) * 32 + fs;
    boff[i] = (wc * 64 + i * 16 + m15) * 32 + fs;
  }

  float4_t acc[4][4];
#pragma unroll
  for (int i = 0; i < 4; ++i)
#pragma unroll
    for (int j = 0; j < 4; ++j) acc[i][j] = (float4_t)0.0f;

  for (int it = 0; it < Ksub; it += 32) {
    gload16(gAh0, lAh0); gload16(gAh1, lAh1);
    gload16(gAl0, lAl0); gload16(gAl1, lAl1);
    gload16(gBh0, lBh0); gload16(gBh1, lBh1);
    gload16(gBl0, lBl0); gload16(gBl1, lBl1);
    gAh0 += 32; gAh1 += 32; gAl0 += 32; gAl1 += 32;
    gBh0 += 32; gBh1 += 32; gBl0 += 32; gBl1 += 32;
    __syncthreads();

    short8_t ah[4], al[4];
#pragma unroll
    for (int i = 0; i < 4; ++i) {
      ah[i] = *(const short8_t*)&Ash[aoff[i]];
      al[i] = *(const short8_t*)&Asl[aoff[i]];
    }
#pragma unroll
    for (int j = 0; j < 4; ++j) {
      short8_t bh = *(const short8_t*)&Bsh[boff[j]];
      short8_t bl = *(const short8_t*)&Bsl[boff[j]];
#pragma unroll
      for (int i = 0; i < 4; ++i) {
        acc[i][j] = __builtin_amdgcn_mfma_f32_16x16x32_bf16(ah[i], bh, acc[i][j], 0, 0, 0);
        acc[i][j] = __builtin_amdgcn_mfma_f32_16x16x32_bf16(ah[i], bl, acc[i][j], 0, 0, 0);
        acc[i][j] = __builtin_amdgcn_mfma_f32_16x16x32_bf16(al[i], bh, acc[i][j], 0, 0, 0);
      }
    }
    __syncthreads();
  }

  short* Chs = (short*)Ch + (size_t)zb * sC;
  short* Cls = (short*)Cl + (size_t)zb * sC;
  float* Cf  = (float*)Ch + (size_t)zb * sC;
#pragma unroll
  for (int i = 0; i < 4; ++i) {
#pragma unroll
    for (int r = 0; r < 4; ++r) {
      int gm = row0 + wr * 64 + i * 16 + q * 4 + r;
      if (gm < M) {
#pragma unroll
        for (int j = 0; j < 4; ++j) {
          int gn = col0 + wc * 64 + j * 16 + m15;
          float v = acc[i][j][r];
          if (DO_TANH) v = fast_tanh(v);
          if (OUT_MODE == 0) {
            atomicAdd(&Cf[(size_t)gm * ldc + gn], v);
          } else {
            short hi, lo; split2(v, hi, lo);
            Chs[(size_t)gm * ldc + gn] = hi;
            Cls[(size_t)gm * ldc + gn] = lo;
          }
        }
      }
    }
  }
}

// ---------------------------------------------------------------------------
// fp16 single-pass NT GEMM, BK=64, async staging, XOR-swizzled LDS.
// MODE 1: fp16 store (betas/alphas; batched via blockIdx.z)
// MODE 2: tanh + column-sum -> agg (V: 16384 rows = [Cat1;Cat2], agg[32][4096])
// ---------------------------------------------------------------------------
template <int MODE>
__global__ __launch_bounds__(256) void gemm_f16(
    const _Float16* __restrict__ A, int lda, long sA,
    const _Float16* __restrict__ B, int ldb, long sB,
    _Float16* __restrict__ C, int ldc, long sC,
    int K, float* __restrict__ agg)
{
  __shared__ __align__(16) _Float16 As[2 * 128 * 32];
  __shared__ __align__(16) _Float16 Bs[2 * 128 * 32];

  const int z = blockIdx.z;
  A += (size_t)z * sA;
  B += (size_t)z * sB;

  const int row0 = blockIdx.x * 128;
  const int col0 = blockIdx.y * 128;
  const int t = threadIdx.x, lane = t & 63, wave = t >> 6;
  const int wr = wave >> 1, wc = wave & 1;
  const int m15 = lane & 15, q = lane >> 4;

  const int srow = wave * 32 + (lane >> 2);
  const int cg   = ((lane & 3) ^ ((lane >> 3) & 3)) * 8;
  const _Float16* gA0 = A + (size_t)(row0 + srow) * lda + cg;
  const _Float16* gA1 = gA0 + (size_t)16 * lda;
  const _Float16* gB0 = B + (size_t)(col0 + srow) * ldb + cg;
  const _Float16* gB1 = gB0 + (size_t)16 * ldb;
  const _Float16* gA0b = gA0 + 32;
  const _Float16* gA1b = gA1 + 32;
  const _Float16* gB0b = gB0 + 32;
  const _Float16* gB1b = gB1 + 32;
  _Float16* lA0  = &As[(wave * 32) * 32];
  _Float16* lA1  = &As[(wave * 32 + 16) * 32];
  _Float16* lB0  = &Bs[(wave * 32) * 32];
  _Float16* lB1  = &Bs[(wave * 32 + 16) * 32];
  _Float16* lA0b = lA0 + 4096;
  _Float16* lA1b = lA1 + 4096;
  _Float16* lB0b = lB0 + 4096;
  _Float16* lB1b = lB1 + 4096;

  const int fs = (q ^ ((m15 >> 1) & 3)) * 8;
  int aoff[4], boff[4];
#pragma unroll
  for (int i = 0; i < 4; ++i) {
    aoff[i] = (wr * 64 + i * 16 + m15) * 32 + fs;
    boff[i] = (wc * 64 + i * 16 + m15) * 32 + fs;
  }

  float4_t acc[4][4];
#pragma unroll
  for (int i = 0; i < 4; ++i)
#pragma unroll
    for (int j = 0; j < 4; ++j) acc[i][j] = (float4_t)0.0f;

  for (int k0 = 0; k0 < K; k0 += 64) {
    gload16(gA0, lA0);  gload16(gA1, lA1);
    gload16(gB0, lB0);  gload16(gB1, lB1);
    gload16(gA0b, lA0b); gload16(gA1b, lA1b);
    gload16(gB0b, lB0b); gload16(gB1b, lB1b);
    gA0 += 64; gA1 += 64; gB0 += 64; gB1 += 64;
    gA0b += 64; gA1b += 64; gB0b += 64; gB1b += 64;
    __syncthreads();

#pragma unroll
    for (int h = 0; h < 2; ++h) {
      half8_t af[4], bfr[4];
#pragma unroll
      for (int i = 0; i < 4; ++i) af[i]  = *(const half8_t*)&As[h * 4096 + aoff[i]];
#pragma unroll
      for (int j = 0; j < 4; ++j) bfr[j] = *(const half8_t*)&Bs[h * 4096 + boff[j]];
#pragma unroll
      for (int i = 0; i < 4; ++i)
#pragma unroll
        for (int j = 0; j < 4; ++j)
          acc[i][j] = __builtin_amdgcn_mfma_f32_16x16x32_f16(af[i], bfr[j], acc[i][j], 0, 0, 0);
    }
    __syncthreads();
  }

  if (MODE == 2) {
    const int half_ = row0 >= 8192;
    const int b     = (row0 & 8191) >> 8;
#pragma unroll
    for (int j = 0; j < 4; ++j) {
      float s = 0.0f;
#pragma unroll
      for (int i = 0; i < 4; ++i)
#pragma unroll
        for (int r = 0; r < 4; ++r) s += fast_tanh(acc[i][j][r]);
      s += __shfl_xor(s, 16);
      s += __shfl_xor(s, 32);
      if (q == 0) {
        int col = col0 + wc * 64 + j * 16 + m15;
        atomicAdd(&agg[(size_t)b * 4096 + half_ * 2048 + col], s);
      }
    }
  } else {
    _Float16* Cp = C + (size_t)z * sC;
#pragma unroll
    for (int i = 0; i < 4; ++i)
#pragma unroll
      for (int r = 0; r < 4; ++r) {
        int gm = row0 + wr * 64 + i * 16 + q * 4 + r;
#pragma unroll
        for (int j = 0; j < 4; ++j) {
          int gn = col0 + wc * 64 + j * 16 + m15;
          Cp[(size_t)gm * ldc + gn] = (_Float16)acc[i][j][r];
        }
      }
  }
}

// --- fused input: P/H -> split bf16 planes + fp16 Cat left half + fp16 PH^T ---
// grid (32 c-tiles, 8 r-tiles, 64): z<32 = P batch z, z>=32 = H batch z-32
__global__ __launch_bounds__(256) void fused_in(
    const float* __restrict__ P, const float* __restrict__ Hh,
    short* __restrict__ oh, short* __restrict__ ol,
    _Float16* __restrict__ cat, _Float16* __restrict__ phT)
{
  __shared__ float tile[32][33];
  const int z = blockIdx.z;
  const float* in = (z < 32 ? P : Hh) + (size_t)(z & 31) * (256 * 1024);
  const int tx = threadIdx.x & 31, ty = threadIdx.x >> 5;
  const int c0 = blockIdx.x * 32, r0 = blockIdx.y * 32;
#pragma unroll
  for (int i = 0; i < 4; ++i) {
    int r = ty + i * 8;
    float v = in[(size_t)(r0 + r) * 1024 + c0 + tx];
    tile[r][tx] = v;
    size_t grow = (size_t)z * 256 + r0 + r;   // 0..16383 ([P;H] row)
    short hi, lo; split2(v, hi, lo);
    oh[grow * 1024 + c0 + tx] = hi;
    ol[grow * 1024 + c0 + tx] = lo;
    cat[grow * 2048 + c0 + tx] = (_Float16)v;
  }
  __syncthreads();
  _Float16* o = phT + (size_t)z * (1024 * 256);
#pragma unroll
  for (int i = 0; i < 4; ++i) {
    int cc = ty + i * 8;
    o[(size_t)(c0 + cc) * 256 + r0 + tx] = (_Float16)tile[tx][cc];
  }
}

// --- fp32 -> split bf16 transpose: out[c][r] ---
__global__ __launch_bounds__(256) void transpose_split(
    const float* __restrict__ in, short* __restrict__ oh, short* __restrict__ ol,
    int R, int C)
{
  __shared__ float tile[32][33];
  const int tx = threadIdx.x & 31, ty = threadIdx.x >> 5;
  const int c0 = blockIdx.x * 32, r0 = blockIdx.y * 32;
#pragma unroll
  for (int i = 0; i < 4; ++i) {
    int r = ty + i * 8;
    tile[r][tx] = in[(size_t)(r0 + r) * C + c0 + tx];
  }
  __syncthreads();
#pragma unroll
  for (int i = 0; i < 4; ++i) {
    int cc = ty + i * 8;
    float v = tile[tx][cc];
    short hi, lo; split2(v, hi, lo);
    size_t o = (size_t)(c0 + cc) * R + r0 + tx;
    oh[o] = hi;
    ol[o] = lo;
  }
}

// --- fp32 -> fp16 transpose: out[c][r] ---
__global__ __launch_bounds__(256) void transpose_f16(
    const float* __restrict__ in, _Float16* __restrict__ out, int R, int C)
{
  __shared__ float tile[32][33];
  const int tx = threadIdx.x & 31, ty = threadIdx.x >> 5;
  const int c0 = blockIdx.x * 32, r0 = blockIdx.y * 32;
#pragma unroll
  for (int i = 0; i < 4; ++i) {
    int r = ty + i * 8;
    tile[r][tx] = in[(size_t)(r0 + r) * C + c0 + tx];
  }
  __syncthreads();
#pragma unroll
  for (int i = 0; i < 4; ++i) {
    int cc = ty + i * 8;
    out[(size_t)(c0 + cc) * R + r0 + tx] = (_Float16)tile[tx][cc];
  }
}

// --- fp16 [256x256] batched transpose (attn -> attnT), bit-copy as short ---
__global__ __launch_bounds__(256) void transpose_b2b(
    const short* __restrict__ in, short* __restrict__ out,
    int R, int C, long sIn, long sOut)
{
  __shared__ short tile[32][33];
  in  += (size_t)blockIdx.z * sIn;
  out += (size_t)blockIdx.z * sOut;
  const int tx = threadIdx.x & 31, ty = threadIdx.x >> 5;
  const int c0 = blockIdx.x * 32, r0 = blockIdx.y * 32;
#pragma unroll
  for (int i = 0; i < 4; ++i) {
    int r = ty + i * 8;
    tile[r][tx] = in[(size_t)(r0 + r) * C + c0 + tx];
  }
  __syncthreads();
#pragma unroll
  for (int i = 0; i < 4; ++i) {
    int cc = ty + i * 8;
    out[(size_t)(c0 + cc) * R + r0 + tx] = tile[tx][cc];
  }
}

__global__ __launch_bounds__(256) void zero_f32(float* __restrict__ p, int n)
{
  int i = blockIdx.x * 256 + threadIdx.x;
  if (i < n) p[i] = 0.0f;
}

// --- softmax over rows of 256 (one wave per row), fp32 -> fp16 ---
__global__ __launch_bounds__(256) void softmax_rows(
    const float* __restrict__ e, _Float16* __restrict__ attn)
{
  const int row  = blockIdx.x * 4 + (threadIdx.x >> 6);
  const int lane = threadIdx.x & 63;
  const float4 v = *(const float4*)&e[(size_t)row * 256 + lane * 4];
  float m = fmaxf(fmaxf(v.x, v.y), fmaxf(v.z, v.w));
#pragma unroll
  for (int off = 32; off; off >>= 1) m = fmaxf(m, __shfl_xor(m, off));
  float e0 = __expf(v.x - m), e1 = __expf(v.y - m);
  float e2 = __expf(v.z - m), e3 = __expf(v.w - m);
  float s = e0 + e1 + e2 + e3;
#pragma unroll
  for (int off = 32; off; off >>= 1) s += __shfl_xor(s, off);
  float inv = 1.0f / s;
  half4_t o;
  o.x = (_Float16)(e0 * inv); o.y = (_Float16)(e1 * inv);
  o.z = (_Float16)(e2 * inv); o.w = (_Float16)(e3 * inv);
  *(half4_t*)&attn[(size_t)row * 256 + lane * 4] = o;
}

// --- fp32 skinny GEMM: part[ks][32][N] = A[32][KA] @ W[KA][N] (k-slice ks) ---
// A reads are wave-uniform -> scalar loads; W reads coalesced over n.
__global__ __launch_bounds__(256) void skinny_gemm(
    const float* __restrict__ A, int lda,
    const float* __restrict__ W, int N, int Kslice,
    float* __restrict__ part)
{
  const int n  = blockIdx.x * 256 + threadIdx.x;
  const int k0 = blockIdx.y * Kslice;
  float acc[32];
#pragma unroll
  for (int m = 0; m < 32; ++m) acc[m] = 0.0f;
  for (int k = k0; k < k0 + Kslice; ++k) {
    float w = W[(size_t)k * N + n];
#pragma unroll
    for (int m = 0; m < 32; ++m)
      acc[m] = fmaf(A[m * lda + k], w, acc[m]);
  }
  float* pp = part + (size_t)blockIdx.y * 32 * N;
#pragma unroll
  for (int m = 0; m < 32; ++m) pp[(size_t)m * N + n] = acc[m];
}

// --- out[i] = tanh(bias[i & 2047] + sum_s part[s*n + i]) ---
__global__ __launch_bounds__(256) void reduce_bias_tanh(
    const float* __restrict__ part, const float* __restrict__ bias,
    float* __restrict__ outp, int n, int slices)
{
  int i = blockIdx.x * 256 + threadIdx.x;
  if (i >= n) return;
  float s = bias[i & 2047];
  for (int sl = 0; sl < slices; ++sl) s += part[(size_t)sl * n + i];
  outp[i] = fast_tanh(s);
}

// --- logits: block b: out[b] = tanh(sum_s c2p[s][b] + b2) @ W3 + b3 ---
__global__ __launch_bounds__(256) void logits_red(
    const float* __restrict__ part, const float* __restrict__ b2,
    const float* __restrict__ W3, const float* __restrict__ b3,
    float* __restrict__ out, int slices)
{
  const int b = blockIdx.x, t = threadIdx.x;
  float p0 = 0.f, p1 = 0.f, p2 = 0.f;
  for (int k = t; k < 2048; k += 256) {
    float a = b2[k];
    for (int sl = 0; sl < slices; ++sl)
      a += part[((size_t)sl * 32 + b) * 2048 + k];
    a = fast_tanh(a);
    p0 += a * W3[k * 3 + 0];
    p1 += a * W3[k * 3 + 1];
    p2 += a * W3[k * 3 + 2];
  }
#pragma unroll
  for (int off = 32; off; off >>= 1) {
    p0 += __shfl_xor(p0, off);
    p1 += __shfl_xor(p1, off);
    p2 += __shfl_xor(p2, off);
  }
  __shared__ float red[4][3];
  if ((t & 63) == 0) {
    red[t >> 6][0] = p0; red[t >> 6][1] = p1; red[t >> 6][2] = p2;
  }
  __syncthreads();
  if (t < 3) out[b * 3 + t] = b3[t] + red[0][t] + red[1][t] + red[2][t] + red[3][t];
}

extern "C" void kernel_launch(void* const* d_in, const int* in_sizes, int n_in,
                              void* d_out, int out_size, void* d_ws, size_t ws_size,
                              hipStream_t stream) {
  (void)in_sizes; (void)n_in; (void)out_size; (void)ws_size;
  const float* P   = (const float*)d_in[0];
  const float* H   = (const float*)d_in[1];
  const float* W_F = (const float*)d_in[2];
  const float* W_G = (const float*)d_in[3];
  const float* W1  = (const float*)d_in[4];
  const float* b1  = (const float*)d_in[5];
  const float* W2  = (const float*)d_in[6];
  const float* b2  = (const float*)d_in[7];
  const float* W3  = (const float*)d_in[8];
  const float* b3  = (const float*)d_in[9];
  float* out = (float*)d_out;

  char* wsp = (char*)d_ws;
  auto alloc = [&](size_t bytes) {
    char* p = wsp;
    wsp += (bytes + 255) & ~(size_t)255;
    return p;
  };
  short*    Pp_h  = (short*)alloc(16384ull * 1024 * 2);     // [P;H] split planes
  short*    Pp_l  = (short*)alloc(16384ull * 1024 * 2);
  _Float16* Cat16 = (_Float16*)alloc(16384ull * 2048 * 2);  // [P|betas ; H|alphas]
  _Float16* PHbT  = (_Float16*)alloc(64ull * 1024 * 256 * 2); // P^T,H^T fp16
  short*    Fbuf  = (short*)alloc(32ull * 1024 * 1024 * 2);   // F split planes
  short*    WFT_h = (short*)alloc(1024ull * 1024 * 2);
  short*    WFT_l = (short*)alloc(1024ull * 1024 * 2);
  _Float16* WGT16 = (_Float16*)alloc(2048ull * 2048 * 2);
  float*    eijs  = (float*)alloc(32ull * 256 * 256 * 4);   // NB: contiguous with
  float*    agg   = (float*)alloc(32ull * 4096 * 4);        //     agg (one zero)
  _Float16* attn  = (_Float16*)alloc(32ull * 256 * 256 * 2);
  _Float16* attnT = (_Float16*)alloc(32ull * 256 * 256 * 2);

  short* F_h = Fbuf;
  short* F_l = Fbuf + 16384ull * 1024;
  _Float16* PbT = PHbT;
  _Float16* HbT = PHbT + 32ull * 1024 * 256;
  // classifier scratch aliases Pp planes (dead after the F GEMM)
  float* c1p = (float*)Pp_h;                 // [32][32][2048] = 8 MB
  float* c2p = c1p + 32ull * 32 * 2048;      // 8 MB
  float* a1f = c2p + 32ull * 32 * 2048;      // [32][2048] fp32

  // 1. upfront zero (eijs+agg contiguous), input fusion, weight transposes
  zero_f32<<<8704, 256, 0, stream>>>(eijs, 32 * 256 * 256 + 32 * 4096);
  fused_in<<<dim3(32, 8, 64), 256, 0, stream>>>(P, H, Pp_h, Pp_l, Cat16, PHbT);
  transpose_split<<<dim3(32, 32, 1), 256, 0, stream>>>(W_F, WFT_h, WFT_l, 1024, 1024);
  transpose_f16<<<dim3(64, 64, 1), 256, 0, stream>>>(W_G, WGT16, 2048, 2048);

  // 2. F = tanh([P;H] @ W_F), split bf16x3 (async staging)
  gemm_nt_split<1, 1><<<dim3(128, 8, 1), 256, 0, stream>>>(
      Pp_h, Pp_l, 1024, 0, WFT_h, WFT_l, 1024, 0,
      F_h, F_l, 1024, 0, 16384, 1024, 1);

  // 3. scores E[z] = F_p[z] @ F_h[z]^T, split bf16x3, split-K x4 (atomic fp32)
  gemm_nt_split<0, 0><<<dim3(2, 2, 128), 256, 0, stream>>>(
      F_h, F_l, 1024, 256 * 1024,
      F_h + 8192ull * 1024, F_l + 8192ull * 1024, 1024, 256 * 1024,
      eijs, nullptr, 256, 65536, 256, 1024, 4);

  // 4. softmax -> fp16 attn; attn^T
  softmax_rows<<<2048, 256, 0, stream>>>(eijs, attn);
  transpose_b2b<<<dim3(8, 8, 32), 256, 0, stream>>>(
      (const short*)attn, (short*)attnT, 256, 256, 65536, 65536);

  // 5. betas = attn @ H -> Cat1 right; alphas = attn^T @ P -> Cat2 right (fp16)
  gemm_f16<1><<<dim3(2, 8, 32), 256, 0, stream>>>(
      attn, 256, 65536, HbT, 256, 1024 * 256,
      Cat16 + 1024, 2048, 256 * 2048, 256, nullptr);
  gemm_f16<1><<<dim3(2, 8, 32), 256, 0, stream>>>(
      attnT, 256, 65536, PbT, 256, 1024 * 256,
      Cat16 + 8192ull * 2048 + 1024, 2048, 256 * 2048, 256, nullptr);

  // 6. V = tanh(Cat @ W_G) fused column-sum -> agg (fp16, BK=64)
  gemm_f16<2><<<dim3(128, 16, 1), 256, 0, stream>>>(
      Cat16, 2048, 0, WGT16, 2048, 0, nullptr, 0, 0, 2048, agg);

  // 7. classifier: fp32 skinny GEMMs (k-sliced partials) + reduce epilogues
  skinny_gemm<<<dim3(8, 32), 256, 0, stream>>>(agg, 4096, W1, 2048, 128, c1p);
  reduce_bias_tanh<<<256, 256, 0, stream>>>(c1p, b1, a1f, 32 * 2048, 32);
  skinny_gemm<<<dim3(8, 32), 256, 0, stream>>>(a1f, 2048, W2, 2048, 64, c2p);
  logits_red<<<32, 256, 0, stream>>>(c2p, b2, W3, b3, out, 32);
}